// Round 9
// baseline (719.108 us; speedup 1.0000x reference)
//
#include <hip/hip_runtime.h>
#include <hip/hip_bf16.h>

#define DD 80
#define CIN 32
#define PLANE (DD*DD)        // 6400
#define VOX (DD*DD*DD)       // 512000
#define NPTS 200000
#define NBUCK 4000           // 10 x 20 x 20 buckets of 8x4x4 voxels
#define HROWS 360            // halo rows per bucket: 10*6*6

typedef __attribute__((ext_vector_type(8))) short bf16x8;
typedef __attribute__((ext_vector_type(4))) float floatx4;

static __device__ __forceinline__ short f2bf(float v) {
    __hip_bfloat16 b = __float2bfloat16(v);
    return *(short*)&b;
}

// async global->LDS 16B copy: lane's 16B lands at ldsbase + lane*16 (wave-uniform base)
static __device__ __forceinline__ void async_copy16(void* lds, const void* g) {
    __builtin_amdgcn_global_load_lds(
        (const __attribute__((address_space(1))) unsigned int*)g,
        (__attribute__((address_space(3))) unsigned int*)lds, 16, 0, 0);
}

// ---------------- K0: convert/permute all weights to bf16 ----------------
__global__ void convert_weights(const float* __restrict__ w2,
                                const float* __restrict__ w_p1,
                                const float* __restrict__ w_p2,
                                const float* __restrict__ w_p3,
                                const float* __restrict__ w_e1,
                                short* __restrict__ wpb, short* __restrict__ w1b,
                                short* __restrict__ w2b, short* __restrict__ w3b,
                                short* __restrict__ wc1) {
    int i = blockIdx.x * 256 + threadIdx.x;      // total 264192
    if (i < 110592) {
        int oc = i / 1728, j = i - oc * 1728;
        int off = j >> 6, ic = j & 63;
        wpb[i] = f2bf(w2[oc * 1728 + ic * 27 + off]);
    } else if (i < 110592 + 16384) {
        int j = i - 110592;
        w1b[j] = f2bf(w_p1[j]);
    } else if (i < 110592 + 16384 + 65536) {
        int j = i - 110592 - 16384;
        w2b[j] = f2bf(w_p2[j]);
    } else if (i < 110592 + 16384 + 65536 + 16384) {
        int j = i - 110592 - 16384 - 65536;
        w3b[j] = f2bf(w_p3[j]);
    } else if (i < 110592 + 16384 + 65536 + 16384 + 55296) {
        int j = i - (110592 + 16384 + 65536 + 16384);   // [off][oc][ic]
        int off = j / 2048, r = j - off * 2048;
        int oc = r >> 5, ic = r & 31;
        wc1[j] = f2bf(w_e1[(oc * 32 + ic) * 27 + off]);
    }
}

// ---------------- sort: bucket points by 8x4x4 voxel block ----------------
__global__ void zero_hist(int* __restrict__ hist) {
    int i = blockIdx.x * 256 + threadIdx.x;
    if (i < 4096) hist[i] = 0;
}

__global__ void hist_kernel(const int* __restrict__ c0, const int* __restrict__ c1,
                            const int* __restrict__ c2, int* __restrict__ hist) {
    int p = blockIdx.x * 256 + threadIdx.x;
    if (p >= NPTS) return;
    int b = (c0[p] >> 3) * 400 + (c1[p] >> 2) * 20 + (c2[p] >> 2);
    atomicAdd(&hist[b], 1);
}

// scan 4096 entries with 1024 threads (4 per thread)
__global__ __launch_bounds__(1024) void scan_kernel(const int* __restrict__ hist,
                                                    int* __restrict__ offs,
                                                    int* __restrict__ start) {
    __shared__ int tmp[1024];
    int t = threadIdx.x;
    int h0 = hist[t * 4], h1 = hist[t * 4 + 1], h2 = hist[t * 4 + 2], h3 = hist[t * 4 + 3];
    int tot = h0 + h1 + h2 + h3;
    tmp[t] = tot;
    __syncthreads();
    for (int s = 1; s < 1024; s <<= 1) {
        int v = (t >= s) ? tmp[t - s] : 0;
        __syncthreads();
        tmp[t] += v;
        __syncthreads();
    }
    int base = tmp[t] - tot;    // exclusive over groups of 4
    offs[t * 4] = base;     start[t * 4] = base;     base += h0;
    offs[t * 4 + 1] = base; start[t * 4 + 1] = base; base += h1;
    offs[t * 4 + 2] = base; start[t * 4 + 2] = base; base += h2;
    offs[t * 4 + 3] = base; start[t * 4 + 3] = base;
}

__global__ void scatter_kernel(const int* __restrict__ c0, const int* __restrict__ c1,
                               const int* __restrict__ c2, int* __restrict__ offs,
                               int* __restrict__ perm) {
    int p = blockIdx.x * 256 + threadIdx.x;
    if (p >= NPTS) return;
    int b = (c0[p] >> 3) * 400 + (c1[p] >> 2) * 20 + (c2[p] >> 2);
    int pos = atomicAdd(&offs[b], 1);
    perm[pos] = p;
}

// ---------------- K0b: transpose img (32,VOX) fp32 -> img_t [vox][32] bf16 ----------------
__global__ __launch_bounds__(256) void transpose_img(
    const float* __restrict__ img, short* __restrict__ img_t)
{
    int v = blockIdx.x * 256 + threadIdx.x;
    if (v >= VOX) return;
    short row[32];
    #pragma unroll
    for (int ic = 0; ic < 32; ic++)
        row[ic] = f2bf(img[(size_t)ic * VOX + v]);
    int4* dst = (int4*)(img_t + (size_t)v * 32);
    #pragma unroll
    for (int c = 0; c < 4; c++) dst[c] = ((int4*)row)[c];
}

// ---------------- K1: conv1 via implicit-GEMM MFMA, async LDS staging ----------------
__global__ __launch_bounds__(256) void conv1_mfma(
    const short* __restrict__ img_t, const short* __restrict__ wc1,
    const float* __restrict__ b1, const short* __restrict__ zeros,
    short* __restrict__ f1)
{
    __shared__ short Alds[3072 * 16 / 2];   // 48 KB

    const int bh = blockIdx.x;
    const int d = bh / DD, h = bh - d * DD;
    const int tid = threadIdx.x;
    const int w = tid >> 6, lane = tid & 63;
    const int q = lane >> 4, lc = lane & 15;

    for (int i = 0; i < 12; i++) {
        int s = (w * 12 + i) * 64 + lane;      // slot 0..3071
        int row = s >> 2, c = s & 3;
        int cs = c ^ (row & 3);                // swizzled source chunk
        int rr = row / 82, v = row - rr * 82;
        int dz = rr / 3, dyy = rr - dz * 3;
        int zz = d + dz - 1, yy = h + dyy - 1, ww = v - 1;
        const short* src = zeros;
        if (row < 738 && (unsigned)zz < DD && (unsigned)yy < DD && (unsigned)ww < DD)
            src = img_t + ((size_t)(zz * PLANE + yy * DD + ww)) * 32 + cs * 8;
        async_copy16(&Alds[(w * 12 + i) * 512], src);
    }
    __syncthreads();

    floatx4 acc[5];
    #pragma unroll
    for (int mt = 0; mt < 5; mt++) acc[mt] = (floatx4){0.f, 0.f, 0.f, 0.f};

    #pragma unroll 3
    for (int off = 0; off < 27; ++off) {
        const int dz = off / 9, rem = off - dz * 9;
        const int dy = rem / 3, dx = rem - dy * 3;
        const int rr = dz * 3 + dy;
        bf16x8 bfr = *(const bf16x8*)(wc1 + ((off * 64 + w * 16 + lc) << 5) + q * 8);
        #pragma unroll
        for (int mt = 0; mt < 5; mt++) {
            const int vv = rr * 82 + mt * 16 + lc + dx;
            bf16x8 afr = *(const bf16x8*)(&Alds[vv * 32 + ((q ^ (vv & 3)) << 3)]);
            acc[mt] = __builtin_amdgcn_mfma_f32_16x16x32_bf16(afr, bfr, acc[mt], 0, 0, 0);
        }
    }

    const int oc = w * 16 + lc;
    const float bias = b1[oc];
    const size_t vbase = (size_t)(d * DD + h) * DD;
    #pragma unroll
    for (int mt = 0; mt < 5; mt++) {
        #pragma unroll
        for (int r = 0; r < 4; r++) {
            const int m = mt * 16 + q * 4 + r;
            float v = acc[mt][r] + bias;
            f1[(vbase + m) * 64 + oc] = f2bf(v > 0.f ? v : 0.f);
        }
    }
}

// ---------------- K2: conv2 via bucket-halo LDS + MFMA ----------------
// block = one 8x4x4 bucket (~50 pts). Halo 10x6x6 rows x 128 B staged once in LDS;
// all 27 neighbor reads per point come from LDS. g written scattered to original order.
__global__ __launch_bounds__(256) void conv2_halo(
    const short* __restrict__ f1s, const short* __restrict__ wpb,
    const float* __restrict__ b2,
    const int* __restrict__ c0, const int* __restrict__ c1, const int* __restrict__ c2,
    const int* __restrict__ perm, const int* __restrict__ start,
    const int* __restrict__ hist, const short* __restrict__ zeros,
    __hip_bfloat16* __restrict__ g)
{
    __shared__ short Alds[HROWS * 64];   // 360 rows x 128 B = 46,080 B

    const int b = blockIdx.x;
    const int bz = b / 400, rem0 = b - bz * 400;
    const int by = rem0 / 20, bx = rem0 - by * 20;
    const int oz = bz * 8 - 1, oy = by * 4 - 1, ox = bx * 4 - 1;
    const int tid = threadIdx.x;
    const int w = tid >> 6, lane = tid & 63;
    const int q = lane >> 4, lc = lane & 15;

    // stage halo: 360 rows x 8 chunks of 16B = 2880 slots, chunk-XOR swizzled at source
    for (int i = 0; i < 12; i++) {
        int sb = (i * 4 + w) * 64;           // wave-uniform slot base
        if (sb < HROWS * 8) {
            int s = sb + lane;
            int row = s >> 3, c = s & 7;
            int hz = row / 36, r2 = row - hz * 36;
            int hy = r2 / 6, hx = r2 - hy * 6;
            int gz = oz + hz, gy = oy + hy, gx = ox + hx;
            const short* src = zeros;
            if ((unsigned)gz < DD && (unsigned)gy < DD && (unsigned)gx < DD)
                src = f1s + ((size_t)(gz * PLANE + gy * DD + gx)) * 64 + ((c ^ (row & 7)) * 8);
            async_copy16(&Alds[sb * 8], src);
        }
    }
    __syncthreads();

    const int s0 = start[b];
    const int cnt = hist[b];

    for (int ig = w; ig * 16 < cnt; ig += 4) {
        int sp = s0 + ig * 16 + lc;
        int spmax = s0 + cnt - 1;
        int spc = sp < spmax ? sp : spmax;
        int p = perm[spc];
        const int lbase = (c0[p] - bz * 8) * 36 + (c1[p] - by * 4) * 6 + (c2[p] - bx * 4);

        floatx4 acc[4];
        #pragma unroll
        for (int nt = 0; nt < 4; nt++) acc[nt] = (floatx4){0.f, 0.f, 0.f, 0.f};

        #pragma unroll 3
        for (int off = 0; off < 27; ++off) {
            const int dz = off / 9, r3 = off - dz * 9;
            const int dy = r3 / 3, dx = r3 - dy * 3;
            const int lrow = lbase + dz * 36 + dy * 6 + dx;

            bf16x8 afr[2];
            #pragma unroll
            for (int ks = 0; ks < 2; ks++) {
                const int pc = (ks * 4 + q) ^ (lrow & 7);
                afr[ks] = *(const bf16x8*)(&Alds[lrow * 64 + pc * 8]);
            }
            bf16x8 bfr[4][2];
            #pragma unroll
            for (int nt = 0; nt < 4; nt++)
                #pragma unroll
                for (int ks = 0; ks < 2; ks++)
                    bfr[nt][ks] = *(const bf16x8*)(wpb + (nt * 16 + lc) * 1728 + off * 64 + ks * 32 + q * 8);

            #pragma unroll
            for (int ks = 0; ks < 2; ks++)
                #pragma unroll
                for (int nt = 0; nt < 4; nt++)
                    acc[nt] = __builtin_amdgcn_mfma_f32_16x16x32_bf16(
                        afr[ks], bfr[nt][ks], acc[nt], 0, 0, 0);
        }

        // epilogue: scatter g rows back to original point ids
        const int gcnt = cnt - ig * 16;
        int pid[4];
        #pragma unroll
        for (int r = 0; r < 4; r++) {
            int li = q * 4 + r;
            pid[r] = (li < gcnt) ? perm[s0 + ig * 16 + li] : -1;
        }
        #pragma unroll
        for (int nt = 0; nt < 4; nt++) {
            const int oc = nt * 16 + lc;
            const float bias = b2[oc];
            #pragma unroll
            for (int r = 0; r < 4; r++) {
                if (pid[r] >= 0) {
                    float v = acc[nt][r] + bias;
                    g[(size_t)pid[r] * 64 + oc] = __float2bfloat16(v > 0.f ? v : 0.f);
                }
            }
        }
    }
}

// ---------------- K3: fused MLP via MFMA. block = 64 points, 4 waves split N ----------------
__global__ __launch_bounds__(256) void mlp_mfma(
    const __hip_bfloat16* __restrict__ g,
    const short* __restrict__ w1b, const float* __restrict__ bp1,
    const short* __restrict__ w2b, const float* __restrict__ bp2,
    const short* __restrict__ w3b, const float* __restrict__ bp3,
    const float* __restrict__ wp4, const float* __restrict__ bp4,
    float* __restrict__ out)
{
    __shared__ short bufA[64 * 256];   // 32 KB: X, then H2
    __shared__ short bufB[64 * 256];   // 32 KB: H1; then fp32 H3 overlay
    float* h3f = (float*)bufB;

    const int tid = threadIdx.x;
    const int pb = blockIdx.x * 64;
    const int w = tid >> 6, lane = tid & 63;
    const int q = lane >> 4, lc = lane & 15;

    const short* gs = (const short*)g;
    #pragma unroll
    for (int it = 0; it < 2; it++) {
        int idx = it * 256 + tid;
        int r = idx >> 3, c = idx & 7;
        int4 v = *(const int4*)(gs + (size_t)(pb + r) * 64 + c * 8);
        *(int4*)(&bufA[r * 256 + (c ^ (r & 7)) * 8]) = v;
    }
    __syncthreads();

    // L1: 64 -> 256, relu
    {
        floatx4 acc[4][4];
        #pragma unroll
        for (int mt = 0; mt < 4; mt++)
            #pragma unroll
            for (int nt = 0; nt < 4; nt++)
                acc[mt][nt] = (floatx4){0.f, 0.f, 0.f, 0.f};

        #pragma unroll
        for (int ks = 0; ks < 2; ks++) {
            bf16x8 bfr[4];
            #pragma unroll
            for (int nt = 0; nt < 4; nt++)
                bfr[nt] = *(const bf16x8*)(w1b + (w * 64 + nt * 16 + lc) * 64 + ks * 32 + q * 8);
            const int c = ks * 4 + q;
            #pragma unroll
            for (int mt = 0; mt < 4; mt++) {
                const int m = mt * 16 + lc;
                bf16x8 afr = *(const bf16x8*)(&bufA[m * 256 + (c ^ (m & 7)) * 8]);
                #pragma unroll
                for (int nt = 0; nt < 4; nt++)
                    acc[mt][nt] = __builtin_amdgcn_mfma_f32_16x16x32_bf16(afr, bfr[nt], acc[mt][nt], 0, 0, 0);
            }
        }
        float bias[4];
        #pragma unroll
        for (int nt = 0; nt < 4; nt++) bias[nt] = bp1[w * 64 + nt * 16 + lc];
        #pragma unroll
        for (int mt = 0; mt < 4; mt++)
            #pragma unroll
            for (int nt = 0; nt < 4; nt++) {
                const int col = w * 64 + nt * 16 + lc;
                #pragma unroll
                for (int r = 0; r < 4; r++) {
                    const int m = mt * 16 + q * 4 + r;
                    float v = acc[mt][nt][r] + bias[nt];
                    v = v > 0.f ? v : 0.f;
                    bufB[m * 256 + (((col >> 3) ^ (m & 7)) * 8 + (col & 7))] = f2bf(v);
                }
            }
    }
    __syncthreads();

    // L2: 256 -> 256, relu
    {
        floatx4 acc[4][4];
        #pragma unroll
        for (int mt = 0; mt < 4; mt++)
            #pragma unroll
            for (int nt = 0; nt < 4; nt++)
                acc[mt][nt] = (floatx4){0.f, 0.f, 0.f, 0.f};

        #pragma unroll
        for (int ks = 0; ks < 8; ks++) {
            bf16x8 bfr[4];
            #pragma unroll
            for (int nt = 0; nt < 4; nt++)
                bfr[nt] = *(const bf16x8*)(w2b + (w * 64 + nt * 16 + lc) * 256 + ks * 32 + q * 8);
            const int c = ks * 4 + q;
            #pragma unroll
            for (int mt = 0; mt < 4; mt++) {
                const int m = mt * 16 + lc;
                const int pc = (c & 24) | ((c & 7) ^ (m & 7));
                bf16x8 afr = *(const bf16x8*)(&bufB[m * 256 + pc * 8]);
                #pragma unroll
                for (int nt = 0; nt < 4; nt++)
                    acc[mt][nt] = __builtin_amdgcn_mfma_f32_16x16x32_bf16(afr, bfr[nt], acc[mt][nt], 0, 0, 0);
            }
        }
        float bias[4];
        #pragma unroll
        for (int nt = 0; nt < 4; nt++) bias[nt] = bp2[w * 64 + nt * 16 + lc];
        __syncthreads();
        #pragma unroll
        for (int mt = 0; mt < 4; mt++)
            #pragma unroll
            for (int nt = 0; nt < 4; nt++) {
                const int col = w * 64 + nt * 16 + lc;
                #pragma unroll
                for (int r = 0; r < 4; r++) {
                    const int m = mt * 16 + q * 4 + r;
                    float v = acc[mt][nt][r] + bias[nt];
                    v = v > 0.f ? v : 0.f;
                    bufA[m * 256 + (((col >> 3) ^ (m & 7)) * 8 + (col & 7))] = f2bf(v);
                }
            }
    }
    __syncthreads();

    // L3: 256 -> 64
    {
        floatx4 acc[4];
        #pragma unroll
        for (int mt = 0; mt < 4; mt++) acc[mt] = (floatx4){0.f, 0.f, 0.f, 0.f};

        #pragma unroll
        for (int ks = 0; ks < 8; ks++) {
            bf16x8 bfr = *(const bf16x8*)(w3b + (w * 16 + lc) * 256 + ks * 32 + q * 8);
            const int c = ks * 4 + q;
            #pragma unroll
            for (int mt = 0; mt < 4; mt++) {
                const int m = mt * 16 + lc;
                const int pc = (c & 24) | ((c & 7) ^ (m & 7));
                bf16x8 afr = *(const bf16x8*)(&bufA[m * 256 + pc * 8]);
                acc[mt] = __builtin_amdgcn_mfma_f32_16x16x32_bf16(afr, bfr, acc[mt], 0, 0, 0);
            }
        }
        const float bias = bp3[w * 16 + lc];
        const int col = w * 16 + lc;
        __syncthreads();
        #pragma unroll
        for (int mt = 0; mt < 4; mt++)
            #pragma unroll
            for (int r = 0; r < 4; r++) {
                const int m = mt * 16 + q * 4 + r;
                h3f[m * 65 + col] = acc[mt][r] + bias;
            }
    }
    __syncthreads();

    // L4: 64 -> 6
    for (int e = tid; e < 384; e += 256) {
        int c = e >> 6, p = e & 63;
        float a = bp4[c];
        const float* wr = wp4 + c * 64;
        const float* xr = h3f + p * 65;
        #pragma unroll 8
        for (int k = 0; k < 64; k++) a += wr[k] * xr[k];
        out[(size_t)c * NPTS + pb + p] = a;
    }
}

extern "C" void kernel_launch(void* const* d_in, const int* in_sizes, int n_in,
                              void* d_out, int out_size, void* d_ws, size_t ws_size,
                              hipStream_t stream) {
    const float* img = (const float*)d_in[0];
    const int* c0 = (const int*)d_in[1];
    const int* c1 = (const int*)d_in[2];
    const int* c2 = (const int*)d_in[3];
    const float* w_enc1 = (const float*)d_in[4];
    const float* b_enc1 = (const float*)d_in[5];
    const float* w_enc2 = (const float*)d_in[6];
    const float* b_enc2 = (const float*)d_in[7];
    const float* w_p1 = (const float*)d_in[8];
    const float* b_p1 = (const float*)d_in[9];
    const float* w_p2 = (const float*)d_in[10];
    const float* b_p2 = (const float*)d_in[11];
    const float* w_p3 = (const float*)d_in[12];
    const float* b_p3 = (const float*)d_in[13];
    const float* w_p4 = (const float*)d_in[14];
    const float* b_p4 = (const float*)d_in[15];
    float* out = (float*)d_out;

    short* f1b = (short*)d_ws;                       // 32,768,000
    short* wpb = f1b + (size_t)VOX * 64;             // 110592
    short* w1b = wpb + 110592;                       // 16384
    short* w2b = w1b + 16384;                        // 65536
    short* w3b = w2b + 65536;                        // 16384
    short* gb  = w3b + 16384;                        // 12,800,000
    short* img_t = gb + (size_t)NPTS * 64;           // 16,384,000
    short* wc1 = img_t + (size_t)VOX * 32;           // 55296
    short* zeros = wc1 + 55296;                      // 32 shorts (64 B zero source)
    int* hist = (int*)(zeros + 32);                  // 4096
    int* offs = hist + 4096;                         // 4096
    int* start = offs + 4096;                        // 4096
    int* perm = start + 4096;                        // 200000

    hipMemsetAsync(zeros, 0, 64, stream);
    convert_weights<<<(264192 + 255) / 256, 256, 0, stream>>>(
        w_enc2, w_p1, w_p2, w_p3, w_enc1, wpb, w1b, w2b, w3b, wc1);
    zero_hist<<<16, 256, 0, stream>>>(hist);
    hist_kernel<<<(NPTS + 255) / 256, 256, 0, stream>>>(c0, c1, c2, hist);
    scan_kernel<<<1, 1024, 0, stream>>>(hist, offs, start);
    scatter_kernel<<<(NPTS + 255) / 256, 256, 0, stream>>>(c0, c1, c2, offs, perm);
    transpose_img<<<(VOX + 255) / 256, 256, 0, stream>>>(img, img_t);
    conv1_mfma<<<DD * DD, 256, 0, stream>>>(img_t, wc1, b_enc1, zeros, f1b);
    conv2_halo<<<NBUCK, 256, 0, stream>>>(
        f1b, wpb, b_enc2, c0, c1, c2, perm, start, hist, zeros, (__hip_bfloat16*)gb);
    mlp_mfma<<<NPTS / 64, 256, 0, stream>>>(
        (const __hip_bfloat16*)gb, w1b, b_p1, w2b, b_p2, w3b, b_p3, w_p4, b_p4, out);
}

// Round 10
// 443.871 us; speedup vs baseline: 1.6201x; 1.6201x over previous
//
#include <hip/hip_runtime.h>
#include <hip/hip_bf16.h>

#define DD 80
#define CIN 32
#define PLANE (DD*DD)        // 6400
#define VOX (DD*DD*DD)       // 512000
#define NPTS 200000

typedef __attribute__((ext_vector_type(8))) short bf16x8;
typedef __attribute__((ext_vector_type(4))) float floatx4;

static __device__ __forceinline__ short f2bf(float v) {
    __hip_bfloat16 b = __float2bfloat16(v);
    return *(short*)&b;
}

// async global->LDS 16B copy: lane's 16B lands at ldsbase + lane*16 (wave-uniform base)
static __device__ __forceinline__ void async_copy16(void* lds, const void* g) {
    __builtin_amdgcn_global_load_lds(
        (const __attribute__((address_space(1))) unsigned int*)g,
        (__attribute__((address_space(3))) unsigned int*)lds, 16, 0, 0);
}

// ---------------- K0: convert/permute all weights to bf16 ----------------
__global__ void convert_weights(const float* __restrict__ w2,
                                const float* __restrict__ w_p1,
                                const float* __restrict__ w_p2,
                                const float* __restrict__ w_p3,
                                const float* __restrict__ w_e1,
                                short* __restrict__ wpb, short* __restrict__ w1b,
                                short* __restrict__ w2b, short* __restrict__ w3b,
                                short* __restrict__ wc1) {
    int i = blockIdx.x * 256 + threadIdx.x;      // total 264192
    if (i < 110592) {
        int oc = i / 1728, j = i - oc * 1728;
        int off = j >> 6, ic = j & 63;
        wpb[i] = f2bf(w2[oc * 1728 + ic * 27 + off]);
    } else if (i < 110592 + 16384) {
        int j = i - 110592;
        w1b[j] = f2bf(w_p1[j]);
    } else if (i < 110592 + 16384 + 65536) {
        int j = i - 110592 - 16384;
        w2b[j] = f2bf(w_p2[j]);
    } else if (i < 110592 + 16384 + 65536 + 16384) {
        int j = i - 110592 - 16384 - 65536;
        w3b[j] = f2bf(w_p3[j]);
    } else if (i < 110592 + 16384 + 65536 + 16384 + 55296) {
        int j = i - (110592 + 16384 + 65536 + 16384);   // [off][oc][ic]
        int off = j / 2048, r = j - off * 2048;
        int oc = r >> 5, ic = r & 31;
        wc1[j] = f2bf(w_e1[(oc * 32 + ic) * 27 + off]);
    }
}

// ---------------- K0b: transpose img (32,VOX) fp32 -> img_t [vox][32] bf16 ----------------
__global__ __launch_bounds__(256) void transpose_img(
    const float* __restrict__ img, short* __restrict__ img_t)
{
    int v = blockIdx.x * 256 + threadIdx.x;
    if (v >= VOX) return;
    short row[32];
    #pragma unroll
    for (int ic = 0; ic < 32; ic++)
        row[ic] = f2bf(img[(size_t)ic * VOX + v]);
    int4* dst = (int4*)(img_t + (size_t)v * 32);
    #pragma unroll
    for (int c = 0; c < 4; c++) dst[c] = ((int4*)row)[c];
}

// ---------------- K1: conv1 via implicit-GEMM MFMA, async LDS staging ----------------
__global__ __launch_bounds__(256) void conv1_mfma(
    const short* __restrict__ img_t, const short* __restrict__ wc1,
    const float* __restrict__ b1, const short* __restrict__ zeros,
    short* __restrict__ f1)
{
    __shared__ short Alds[3072 * 16 / 2];   // 48 KB

    const int bh = blockIdx.x;
    const int d = bh / DD, h = bh - d * DD;
    const int tid = threadIdx.x;
    const int w = tid >> 6, lane = tid & 63;
    const int q = lane >> 4, lc = lane & 15;

    for (int i = 0; i < 12; i++) {
        int s = (w * 12 + i) * 64 + lane;      // slot 0..3071
        int row = s >> 2, c = s & 3;
        int cs = c ^ (row & 3);                // swizzled source chunk
        int rr = row / 82, v = row - rr * 82;
        int dz = rr / 3, dyy = rr - dz * 3;
        int zz = d + dz - 1, yy = h + dyy - 1, ww = v - 1;
        const short* src = zeros;
        if (row < 738 && (unsigned)zz < DD && (unsigned)yy < DD && (unsigned)ww < DD)
            src = img_t + ((size_t)(zz * PLANE + yy * DD + ww)) * 32 + cs * 8;
        async_copy16(&Alds[(w * 12 + i) * 512], src);
    }
    __syncthreads();

    floatx4 acc[5];
    #pragma unroll
    for (int mt = 0; mt < 5; mt++) acc[mt] = (floatx4){0.f, 0.f, 0.f, 0.f};

    #pragma unroll 3
    for (int off = 0; off < 27; ++off) {
        const int dz = off / 9, rem = off - dz * 9;
        const int dy = rem / 3, dx = rem - dy * 3;
        const int rr = dz * 3 + dy;
        bf16x8 bfr = *(const bf16x8*)(wc1 + ((off * 64 + w * 16 + lc) << 5) + q * 8);
        #pragma unroll
        for (int mt = 0; mt < 5; mt++) {
            const int vv = rr * 82 + mt * 16 + lc + dx;
            bf16x8 afr = *(const bf16x8*)(&Alds[vv * 32 + ((q ^ (vv & 3)) << 3)]);
            acc[mt] = __builtin_amdgcn_mfma_f32_16x16x32_bf16(afr, bfr, acc[mt], 0, 0, 0);
        }
    }

    const int oc = w * 16 + lc;
    const float bias = b1[oc];
    const size_t vbase = (size_t)(d * DD + h) * DD;
    #pragma unroll
    for (int mt = 0; mt < 5; mt++) {
        #pragma unroll
        for (int r = 0; r < 4; r++) {
            const int m = mt * 16 + q * 4 + r;
            float v = acc[mt][r] + bias;
            f1[(vbase + m) * 64 + oc] = f2bf(v > 0.f ? v : 0.f);
        }
    }
}

// ---------------- K2: conv2, direct-gather A + LDS-shared B (double-buffered) ----------------
// block = 256 pts (4 waves x 64 pts x 64 oc). Per offset: B (8 KB) staged once via async
// global_load_lds, shared by all waves; A gathered direct to registers (no LDS round-trip).
__global__ __launch_bounds__(256) void conv2_mfma(
    const short* __restrict__ f1s, const short* __restrict__ wpb,
    const float* __restrict__ b2,
    const int* __restrict__ c0, const int* __restrict__ c1, const int* __restrict__ c2,
    __hip_bfloat16* __restrict__ g)
{
    __shared__ short Blds[2][512 * 8];   // 2 x 8 KB, 16B slots; slot s holds chunk (s&7)^(oc&7) of oc=s>>3

    const int tid = threadIdx.x;
    const int w = tid >> 6, lane = tid & 63;
    const int q = lane >> 4, lc = lane & 15;
    const int pw = blockIdx.x * 256 + w * 64;    // wave's point base

    int rowbase[4];
    int rowmask[4];
    #pragma unroll
    for (int mt = 0; mt < 4; mt++) {
        int p = pw + mt * 16 + lc;
        if (p > NPTS - 1) p = NPTS - 1;
        int z = c0[p], y = c1[p], x = c2[p];
        rowbase[mt] = (z * PLANE + y * DD + x) * 64;
        int m = 0;
        #pragma unroll
        for (int off = 0; off < 27; off++) {
            int dz = off / 9, dy = (off / 3) % 3, dx = off % 3;
            int ok = ((unsigned)(z + dz - 1) < DD) & ((unsigned)(y + dy - 1) < DD) &
                     ((unsigned)(x + dx - 1) < DD);
            m |= ok << off;
        }
        rowmask[mt] = m;
    }

    floatx4 acc[4][4];
    #pragma unroll
    for (int mt = 0; mt < 4; mt++)
        #pragma unroll
        for (int nt = 0; nt < 4; nt++)
            acc[mt][nt] = (floatx4){0.f, 0.f, 0.f, 0.f};

    // stage B for offset 0
    #pragma unroll
    for (int it = 0; it < 2; it++) {
        int sb = it * 256 + w * 64;
        int s = sb + lane;
        int oc = s >> 3, cs = (s & 7) ^ (oc & 7);
        async_copy16(&Blds[0][sb * 8], wpb + oc * 1728 + 0 * 64 + cs * 8);
    }
    __syncthreads();

    for (int off = 0; off < 27; ++off) {
        // prefetch B for next offset into the other buffer
        if (off + 1 < 27) {
            #pragma unroll
            for (int it = 0; it < 2; it++) {
                int sb = it * 256 + w * 64;
                int s = sb + lane;
                int oc = s >> 3, cs = (s & 7) ^ (oc & 7);
                async_copy16(&Blds[(off + 1) & 1][sb * 8],
                             wpb + oc * 1728 + (off + 1) * 64 + cs * 8);
            }
        }

        const int dz = off / 9, rem = off - dz * 9;
        const int dy = rem / 3, dx = rem - dy * 3;
        const int delta = ((dz - 1) * PLANE + (dy - 1) * DD + (dx - 1)) * 64;

        // A-frags: 4 mt x 2 ks masked direct gathers (16 B each)
        bf16x8 afr[4][2];
        #pragma unroll
        for (int mt = 0; mt < 4; mt++) {
            const int valid = (rowmask[mt] >> off) & 1;
            #pragma unroll
            for (int ks = 0; ks < 2; ks++) {
                bf16x8 v = (bf16x8)(short)0;
                if (valid)
                    v = *(const bf16x8*)(f1s + rowbase[mt] + delta + ks * 32 + q * 8);
                afr[mt][ks] = v;
            }
        }
        // B-frags from LDS: slot = oc*8 + (kc ^ (oc&7)), oc = nt*16+lc, kc = ks*4+q
        bf16x8 bfr[4][2];
        #pragma unroll
        for (int nt = 0; nt < 4; nt++) {
            const int oc = nt * 16 + lc;
            #pragma unroll
            for (int ks = 0; ks < 2; ks++) {
                const int slot = oc * 8 + ((ks * 4 + q) ^ (oc & 7));
                bfr[nt][ks] = *(const bf16x8*)(&Blds[off & 1][slot * 8]);
            }
        }

        #pragma unroll
        for (int ks = 0; ks < 2; ks++)
            #pragma unroll
            for (int mt = 0; mt < 4; mt++)
                #pragma unroll
                for (int nt = 0; nt < 4; nt++)
                    acc[mt][nt] = __builtin_amdgcn_mfma_f32_16x16x32_bf16(
                        afr[mt][ks], bfr[nt][ks], acc[mt][nt], 0, 0, 0);

        __syncthreads();   // buf[off&1] consumed by all; prefetch for off+1 has landed
    }

    #pragma unroll
    for (int nt = 0; nt < 4; nt++) {
        const int oc = nt * 16 + lc;
        const float bias = b2[oc];
        #pragma unroll
        for (int mt = 0; mt < 4; mt++) {
            const int pt = pw + mt * 16 + q * 4;
            #pragma unroll
            for (int r = 0; r < 4; r++) {
                if (pt + r < NPTS) {
                    float v = acc[mt][nt][r] + bias;
                    g[(size_t)(pt + r) * 64 + oc] = __float2bfloat16(v > 0.f ? v : 0.f);
                }
            }
        }
    }
}

// ---------------- K3: fused MLP via MFMA. block = 64 points, 4 waves split N ----------------
__global__ __launch_bounds__(256) void mlp_mfma(
    const __hip_bfloat16* __restrict__ g,
    const short* __restrict__ w1b, const float* __restrict__ bp1,
    const short* __restrict__ w2b, const float* __restrict__ bp2,
    const short* __restrict__ w3b, const float* __restrict__ bp3,
    const float* __restrict__ wp4, const float* __restrict__ bp4,
    float* __restrict__ out)
{
    __shared__ short bufA[64 * 256];   // 32 KB: X, then H2
    __shared__ short bufB[64 * 256];   // 32 KB: H1; then fp32 H3 overlay
    float* h3f = (float*)bufB;

    const int tid = threadIdx.x;
    const int pb = blockIdx.x * 64;
    const int w = tid >> 6, lane = tid & 63;
    const int q = lane >> 4, lc = lane & 15;

    const short* gs = (const short*)g;
    #pragma unroll
    for (int it = 0; it < 2; it++) {
        int idx = it * 256 + tid;
        int r = idx >> 3, c = idx & 7;
        int4 v = *(const int4*)(gs + (size_t)(pb + r) * 64 + c * 8);
        *(int4*)(&bufA[r * 256 + (c ^ (r & 7)) * 8]) = v;
    }
    __syncthreads();

    // L1: 64 -> 256, relu
    {
        floatx4 acc[4][4];
        #pragma unroll
        for (int mt = 0; mt < 4; mt++)
            #pragma unroll
            for (int nt = 0; nt < 4; nt++)
                acc[mt][nt] = (floatx4){0.f, 0.f, 0.f, 0.f};

        #pragma unroll
        for (int ks = 0; ks < 2; ks++) {
            bf16x8 bfr[4];
            #pragma unroll
            for (int nt = 0; nt < 4; nt++)
                bfr[nt] = *(const bf16x8*)(w1b + (w * 64 + nt * 16 + lc) * 64 + ks * 32 + q * 8);
            const int c = ks * 4 + q;
            #pragma unroll
            for (int mt = 0; mt < 4; mt++) {
                const int m = mt * 16 + lc;
                bf16x8 afr = *(const bf16x8*)(&bufA[m * 256 + (c ^ (m & 7)) * 8]);
                #pragma unroll
                for (int nt = 0; nt < 4; nt++)
                    acc[mt][nt] = __builtin_amdgcn_mfma_f32_16x16x32_bf16(afr, bfr[nt], acc[mt][nt], 0, 0, 0);
            }
        }
        float bias[4];
        #pragma unroll
        for (int nt = 0; nt < 4; nt++) bias[nt] = bp1[w * 64 + nt * 16 + lc];
        #pragma unroll
        for (int mt = 0; mt < 4; mt++)
            #pragma unroll
            for (int nt = 0; nt < 4; nt++) {
                const int col = w * 64 + nt * 16 + lc;
                #pragma unroll
                for (int r = 0; r < 4; r++) {
                    const int m = mt * 16 + q * 4 + r;
                    float v = acc[mt][nt][r] + bias[nt];
                    v = v > 0.f ? v : 0.f;
                    bufB[m * 256 + (((col >> 3) ^ (m & 7)) * 8 + (col & 7))] = f2bf(v);
                }
            }
    }
    __syncthreads();

    // L2: 256 -> 256, relu
    {
        floatx4 acc[4][4];
        #pragma unroll
        for (int mt = 0; mt < 4; mt++)
            #pragma unroll
            for (int nt = 0; nt < 4; nt++)
                acc[mt][nt] = (floatx4){0.f, 0.f, 0.f, 0.f};

        #pragma unroll
        for (int ks = 0; ks < 8; ks++) {
            bf16x8 bfr[4];
            #pragma unroll
            for (int nt = 0; nt < 4; nt++)
                bfr[nt] = *(const bf16x8*)(w2b + (w * 64 + nt * 16 + lc) * 256 + ks * 32 + q * 8);
            const int c = ks * 4 + q;
            #pragma unroll
            for (int mt = 0; mt < 4; mt++) {
                const int m = mt * 16 + lc;
                const int pc = (c & 24) | ((c & 7) ^ (m & 7));
                bf16x8 afr = *(const bf16x8*)(&bufB[m * 256 + pc * 8]);
                #pragma unroll
                for (int nt = 0; nt < 4; nt++)
                    acc[mt][nt] = __builtin_amdgcn_mfma_f32_16x16x32_bf16(afr, bfr[nt], acc[mt][nt], 0, 0, 0);
            }
        }
        float bias[4];
        #pragma unroll
        for (int nt = 0; nt < 4; nt++) bias[nt] = bp2[w * 64 + nt * 16 + lc];
        __syncthreads();
        #pragma unroll
        for (int mt = 0; mt < 4; mt++)
            #pragma unroll
            for (int nt = 0; nt < 4; nt++) {
                const int col = w * 64 + nt * 16 + lc;
                #pragma unroll
                for (int r = 0; r < 4; r++) {
                    const int m = mt * 16 + q * 4 + r;
                    float v = acc[mt][nt][r] + bias[nt];
                    v = v > 0.f ? v : 0.f;
                    bufA[m * 256 + (((col >> 3) ^ (m & 7)) * 8 + (col & 7))] = f2bf(v);
                }
            }
    }
    __syncthreads();

    // L3: 256 -> 64
    {
        floatx4 acc[4];
        #pragma unroll
        for (int mt = 0; mt < 4; mt++) acc[mt] = (floatx4){0.f, 0.f, 0.f, 0.f};

        #pragma unroll
        for (int ks = 0; ks < 8; ks++) {
            bf16x8 bfr = *(const bf16x8*)(w3b + (w * 16 + lc) * 256 + ks * 32 + q * 8);
            const int c = ks * 4 + q;
            #pragma unroll
            for (int mt = 0; mt < 4; mt++) {
                const int m = mt * 16 + lc;
                const int pc = (c & 24) | ((c & 7) ^ (m & 7));
                bf16x8 afr = *(const bf16x8*)(&bufA[m * 256 + pc * 8]);
                acc[mt] = __builtin_amdgcn_mfma_f32_16x16x32_bf16(afr, bfr, acc[mt], 0, 0, 0);
            }
        }
        const float bias = bp3[w * 16 + lc];
        const int col = w * 16 + lc;
        __syncthreads();
        #pragma unroll
        for (int mt = 0; mt < 4; mt++)
            #pragma unroll
            for (int r = 0; r < 4; r++) {
                const int m = mt * 16 + q * 4 + r;
                h3f[m * 65 + col] = acc[mt][r] + bias;
            }
    }
    __syncthreads();

    // L4: 64 -> 6
    for (int e = tid; e < 384; e += 256) {
        int c = e >> 6, p = e & 63;
        float a = bp4[c];
        const float* wr = wp4 + c * 64;
        const float* xr = h3f + p * 65;
        #pragma unroll 8
        for (int k = 0; k < 64; k++) a += wr[k] * xr[k];
        out[(size_t)c * NPTS + pb + p] = a;
    }
}

extern "C" void kernel_launch(void* const* d_in, const int* in_sizes, int n_in,
                              void* d_out, int out_size, void* d_ws, size_t ws_size,
                              hipStream_t stream) {
    const float* img = (const float*)d_in[0];
    const int* c0 = (const int*)d_in[1];
    const int* c1 = (const int*)d_in[2];
    const int* c2 = (const int*)d_in[3];
    const float* w_enc1 = (const float*)d_in[4];
    const float* b_enc1 = (const float*)d_in[5];
    const float* w_enc2 = (const float*)d_in[6];
    const float* b_enc2 = (const float*)d_in[7];
    const float* w_p1 = (const float*)d_in[8];
    const float* b_p1 = (const float*)d_in[9];
    const float* w_p2 = (const float*)d_in[10];
    const float* b_p2 = (const float*)d_in[11];
    const float* w_p3 = (const float*)d_in[12];
    const float* b_p3 = (const float*)d_in[13];
    const float* w_p4 = (const float*)d_in[14];
    const float* b_p4 = (const float*)d_in[15];
    float* out = (float*)d_out;

    short* f1b = (short*)d_ws;                       // 32,768,000
    short* wpb = f1b + (size_t)VOX * 64;             // 110592
    short* w1b = wpb + 110592;                       // 16384
    short* w2b = w1b + 16384;                        // 65536
    short* w3b = w2b + 65536;                        // 16384
    short* gb  = w3b + 16384;                        // 12,800,000
    short* img_t = gb + (size_t)NPTS * 64;           // 16,384,000
    short* wc1 = img_t + (size_t)VOX * 32;           // 55296
    short* zeros = wc1 + 55296;                      // 32 shorts (64 B zero source)

    hipMemsetAsync(zeros, 0, 64, stream);
    convert_weights<<<(264192 + 255) / 256, 256, 0, stream>>>(
        w_enc2, w_p1, w_p2, w_p3, w_enc1, wpb, w1b, w2b, w3b, wc1);
    transpose_img<<<(VOX + 255) / 256, 256, 0, stream>>>(img, img_t);
    conv1_mfma<<<DD * DD, 256, 0, stream>>>(img_t, wc1, b_enc1, zeros, f1b);
    conv2_mfma<<<(NPTS + 255) / 256, 256, 0, stream>>>(
        f1b, wpb, b_enc2, c0, c1, c2, (__hip_bfloat16*)gb);
    mlp_mfma<<<NPTS / 64, 256, 0, stream>>>(
        (const __hip_bfloat16*)gb, w1b, b_p1, w2b, b_p2, w3b, b_p3, w_p4, b_p4, out);
}